// Round 7
// baseline (114.871 us; speedup 1.0000x reference)
//
#include <hip/hip_runtime.h>

#define IMG 128
#define PLANE (IMG * IMG)
#define VOLSZ (IMG * IMG * IMG)

// One block per (crop, d_o): 256 threads = 4 waves; lane = w_out; each wave
// handles 16 of the 64 h rows. Per iter the wave needs 4 input rows
// (d0/d1 x h0/h1) at fixed offsets from one scalar rh0; one cooperative
// global_load_dwordx4 covers 4 rows x 64 cols (2 loads if segment spans >64
// slots). DOUBLE-BUFFERED LDS (parity it&1) breaks the WAR hazard that
// serialized iterations, and a depth-2 register prefetch hides L2/HBM
// latency under two iterations of compute.
//
// Index-clamp identity: i0' = min(i0, sz-2), fr' = src - i0'; reference's
// i1-clamp only fires at fr = 0 where fr' = 1 reproduces seg[sz-1] exactly.
__global__ __launch_bounds__(256) void crop_resize_kernel(
    const float* __restrict__ x,      // (4,1,128,128,128) f32
    const int* __restrict__ sizes,    // (4,64) i32
    const int* __restrict__ starts,   // (4,64,3) i32
    float* __restrict__ out)          // (256,64,64,64) f32
{
    __shared__ float sbuf[4][2][512]; // per-wave double buffer (16 KB)

    // XCD-chunked swizzle (16384 blocks, %8==0 -> bijective)
    int bid  = blockIdx.x;
    int swz  = (bid & 7) * 2048 + (bid >> 3);
    int crop = swz >> 6;
    int d_o  = swz & 63;
    int b    = crop >> 6;

    int sz  = sizes[crop];            // wave-uniform -> scalar
    int s_d = starts[crop * 3 + 0];
    int s_h = starts[crop * 3 + 1];
    int s_w = starts[crop * 3 + 2];

    float szf   = (float)sz;
    float scale = szf * (1.0f / 64.0f);
    float szm1  = szf - 1.0f;
    int   szm2  = sz - 2;

    int lane = threadIdx.x & 63;
    int wid  = __builtin_amdgcn_readfirstlane((int)threadIdx.x >> 6);

    // per-lane (i0', fr') for j = lane — shared by w and h axes
    float srcj = ((float)lane + 0.5f) * scale - 0.5f;
    srcj = fminf(fmaxf(srcj, 0.0f), szm1);
    int   i0p = min((int)srcj, szm2);
    float frp = srcj - (float)i0p;
    float ww = frp, omww = 1.0f - frp;

    int ho0 = (s_h + i0p) * IMG;      // h row offset (broadcast via readlane)

    // d axis (uniform)
    float srcd = ((float)d_o + 0.5f) * scale - 0.5f;
    srcd = fminf(fmaxf(srcd, 0.0f), szm1);
    int   di0p = min((int)srcd, szm2);
    float wd   = srcd - (float)di0p;

    int base0 = s_w & ~3;             // 16B-aligned anchor
    int phase = s_w & 3;

    const float* prow = x + (long long)b * VOLSZ + (s_d + di0p) * PLANE + base0;

    // cooperative loader geometry
    int rsel   = lane >> 4;                       // 0..3: (d,h) row select
    int k4     = (lane & 15) << 2;                // float4 column
    int rowoff = (rsel & 1) * IMG + (rsel >> 1) * PLANE;
    int gA = min(base0 + k4,      IMG - 4) - base0;   // clamped, 16B-aligned
    int gB = min(base0 + 64 + k4, IMG - 4) - base0;

    int woffA = rsel * 128 + gA;
    int woffB = rsel * 128 + gB;
    int eidx  = i0p + phase;          // loop-invariant extraction slot

    float* wb0 = sbuf[wid][0];
    float* wb1 = sbuf[wid][1];

    float* orow = out + ((long long)crop * 64 + d_o) * 4096 + lane;

    #define RLANE_I(v, l)  __builtin_amdgcn_readlane((v), (l))
    #define RLANE_F(v, l)  __int_as_float(__builtin_amdgcn_readlane(__float_as_int(v), (l)))

    if (sz + phase > 64) {            // two-load path
        float4 cA, cB, nA, nB;
        {
            const float* s0 = prow + RLANE_I(ho0, wid) + rowoff;
            cA = *(const float4*)(s0 + gA);
            cB = *(const float4*)(s0 + gB);
            const float* s1 = prow + RLANE_I(ho0, wid + 4) + rowoff;
            nA = *(const float4*)(s1 + gA);
            nB = *(const float4*)(s1 + gB);
        }
        #pragma unroll
        for (int it = 0; it < 16; ++it) {
            float4 fA = nA, fB = nB;
            if (it < 14) {
                const float* sn = prow + RLANE_I(ho0, wid + (it + 2) * 4) + rowoff;
                fA = *(const float4*)(sn + gA);
                fB = *(const float4*)(sn + gB);
            }
            float* wb = (it & 1) ? wb1 : wb0;
            *(float4*)(wb + woffA) = cA;
            *(float4*)(wb + woffB) = cB;

            float wh = RLANE_F(frp, wid + it * 4);

            float a0 = wb[eidx],        a1 = wb[eidx + 1];
            float b0 = wb[128 + eidx],  b1 = wb[128 + eidx + 1];
            float c0 = wb[256 + eidx],  c1 = wb[256 + eidx + 1];
            float d0 = wb[384 + eidx],  d1 = wb[384 + eidx + 1];

            float v00 = a0 * omww + a1 * ww;
            float v01 = b0 * omww + b1 * ww;
            float v10 = c0 * omww + c1 * ww;
            float v11 = d0 * omww + d1 * ww;
            float e0 = v00 + (v01 - v00) * wh;
            float e1 = v10 + (v11 - v10) * wh;
            __builtin_nontemporal_store(e0 + (e1 - e0) * wd,
                                        &orow[(wid + it * 4) * 64]);
            cA = nA; cB = nB; nA = fA; nB = fB;
        }
    } else {                          // one-load path
        float4 cA, nA;
        {
            const float* s0 = prow + RLANE_I(ho0, wid) + rowoff;
            cA = *(const float4*)(s0 + gA);
            const float* s1 = prow + RLANE_I(ho0, wid + 4) + rowoff;
            nA = *(const float4*)(s1 + gA);
        }
        #pragma unroll
        for (int it = 0; it < 16; ++it) {
            float4 fA = nA;
            if (it < 14) {
                const float* sn = prow + RLANE_I(ho0, wid + (it + 2) * 4) + rowoff;
                fA = *(const float4*)(sn + gA);
            }
            float* wb = (it & 1) ? wb1 : wb0;
            *(float4*)(wb + woffA) = cA;

            float wh = RLANE_F(frp, wid + it * 4);

            float a0 = wb[eidx],        a1 = wb[eidx + 1];
            float b0 = wb[128 + eidx],  b1 = wb[128 + eidx + 1];
            float c0 = wb[256 + eidx],  c1 = wb[256 + eidx + 1];
            float d0 = wb[384 + eidx],  d1 = wb[384 + eidx + 1];

            float v00 = a0 * omww + a1 * ww;
            float v01 = b0 * omww + b1 * ww;
            float v10 = c0 * omww + c1 * ww;
            float v11 = d0 * omww + d1 * ww;
            float e0 = v00 + (v01 - v00) * wh;
            float e1 = v10 + (v11 - v10) * wh;
            __builtin_nontemporal_store(e0 + (e1 - e0) * wd,
                                        &orow[(wid + it * 4) * 64]);
            cA = nA; nA = fA;
        }
    }
    #undef RLANE_I
    #undef RLANE_F
}

extern "C" void kernel_launch(void* const* d_in, const int* in_sizes, int n_in,
                              void* d_out, int out_size, void* d_ws, size_t ws_size,
                              hipStream_t stream) {
    const float* x      = (const float*)d_in[0];
    const int*   sizes  = (const int*)d_in[1];
    const int*   starts = (const int*)d_in[2];
    float*       out    = (float*)d_out;

    int blocks = 256 * 64;   // (crop, d_o)
    crop_resize_kernel<<<blocks, 256, 0, stream>>>(x, sizes, starts, out);
}